// Round 1
// baseline (652.277 us; speedup 1.0000x reference)
//
#include <hip/hip_runtime.h>
#include <math.h>

#define M_TOK 1024   // B*S
#define DM    2048   // d_model
#define NH    256    // heads
#define HD    8      // head dim

#define TM 64
#define TN 64
#define TK 32

// C[M x DM] = A[M x DM] @ W[DM x DM] + bias, three weight/output sets fused
// (which = blockIdx.x / 32). For a single GEMM, pass the same set three times
// and launch grid.x = 32.
__global__ __launch_bounds__(256) void gemm3(
    const float* __restrict__ A,
    const float* __restrict__ W0, const float* __restrict__ B0, float* __restrict__ C0,
    const float* __restrict__ W1, const float* __restrict__ B1, float* __restrict__ C1,
    const float* __restrict__ W2, const float* __restrict__ B2, float* __restrict__ C2)
{
    __shared__ float As[TK][TM + 4];   // +4 pad: keeps float4 alignment, breaks stride
    __shared__ float Bs[TK][TN];

    const int nb    = DM / TN;                 // 32 col-blocks per matrix
    const int which = blockIdx.x / nb;
    const int bn    = (blockIdx.x % nb) * TN;
    const int bm    = blockIdx.y * TM;

    const float* W    = (which == 0) ? W0 : (which == 1) ? W1 : W2;
    const float* bias = (which == 0) ? B0 : (which == 1) ? B1 : B2;
    float*       C    = (which == 0) ? C0 : (which == 1) ? C1 : C2;

    const int tid = threadIdx.x;
    const int tx  = tid & 15;          // 0..15 -> 4 cols each
    const int ty  = tid >> 4;          // 0..15 -> 4 rows each

    // A-tile load indexing: 64 rows x 32 k, float4 per thread x2
    const int a_r = tid >> 3;          // 0..31
    const int a_c = (tid & 7) << 2;    // 0,4,...,28
    // B-tile load indexing: 32 k x 64 n, float4 per thread x2
    const int b_k = tid >> 4;          // 0..15
    const int b_n = (tid & 15) << 2;   // 0,4,...,60

    float acc[4][4] = {};

    for (int k0 = 0; k0 < DM; k0 += TK) {
        const float4 av0 = *(const float4*)&A[(size_t)(bm + a_r)      * DM + k0 + a_c];
        const float4 av1 = *(const float4*)&A[(size_t)(bm + a_r + 32) * DM + k0 + a_c];
        const float4 bv0 = *(const float4*)&W[(size_t)(k0 + b_k)      * DM + bn + b_n];
        const float4 bv1 = *(const float4*)&W[(size_t)(k0 + b_k + 16) * DM + bn + b_n];

        __syncthreads();   // previous tile's reads done before overwrite

        As[a_c + 0][a_r] = av0.x;
        As[a_c + 1][a_r] = av0.y;
        As[a_c + 2][a_r] = av0.z;
        As[a_c + 3][a_r] = av0.w;
        As[a_c + 0][a_r + 32] = av1.x;
        As[a_c + 1][a_r + 32] = av1.y;
        As[a_c + 2][a_r + 32] = av1.z;
        As[a_c + 3][a_r + 32] = av1.w;
        *(float4*)&Bs[b_k][b_n]      = bv0;
        *(float4*)&Bs[b_k + 16][b_n] = bv1;

        __syncthreads();

        #pragma unroll
        for (int kk = 0; kk < TK; ++kk) {
            const float4 a = *(const float4*)&As[kk][ty << 2];
            const float4 b = *(const float4*)&Bs[kk][tx << 2];
            const float aa[4] = {a.x, a.y, a.z, a.w};
            const float bb[4] = {b.x, b.y, b.z, b.w};
            #pragma unroll
            for (int i = 0; i < 4; ++i)
                #pragma unroll
                for (int j = 0; j < 4; ++j)
                    acc[i][j] += aa[i] * bb[j];
        }
    }

    #pragma unroll
    for (int i = 0; i < 4; ++i) {
        const int row = bm + (ty << 2) + i;
        const int col = bn + (tx << 2);
        float4 out;
        out.x = acc[i][0] + bias[col + 0];
        out.y = acc[i][1] + bias[col + 1];
        out.z = acc[i][2] + bias[col + 2];
        out.w = acc[i][3] + bias[col + 3];
        *(float4*)&C[(size_t)row * DM + col] = out;
    }
}

// Per-token head-mixing attention: one block per token, one thread per head.
// S[h,g] = (q_h . k_g)/sqrt(8); A = softmax_g; O[h,:] = sum_g A[h,g] v[g,:]
__global__ __launch_bounds__(256) void attn(
    const float* __restrict__ Q, const float* __restrict__ K,
    const float* __restrict__ V, float* __restrict__ O)
{
    __shared__ float qs[DM];
    __shared__ float ks[DM];
    __shared__ float vs[DM];

    const int t = blockIdx.x;          // token
    const int h = threadIdx.x;         // head

    // stage q,k,v rows (2048 floats each) with float4 x2 per thread
    {
        const float4* qg = (const float4*)(Q + (size_t)t * DM);
        const float4* kg = (const float4*)(K + (size_t)t * DM);
        const float4* vg = (const float4*)(V + (size_t)t * DM);
        float4* q4 = (float4*)qs; float4* k4 = (float4*)ks; float4* v4 = (float4*)vs;
        q4[h] = qg[h]; q4[h + 256] = qg[h + 256];
        k4[h] = kg[h]; k4[h + 256] = kg[h + 256];
        v4[h] = vg[h]; v4[h + 256] = vg[h + 256];
    }
    __syncthreads();

    float qh[HD];
    #pragma unroll
    for (int d = 0; d < HD; ++d) qh[d] = qs[h * HD + d];

    const float scale = 0.35355339059327373f;   // 1/sqrt(8)
    const float4* k4 = (const float4*)ks;
    const float4* v4 = (const float4*)vs;

    // pass 1: row max
    float m = -1e30f;
    for (int g = 0; g < NH; ++g) {
        const float4 ka = k4[g * 2], kb = k4[g * 2 + 1];
        float s = qh[0]*ka.x + qh[1]*ka.y + qh[2]*ka.z + qh[3]*ka.w
                + qh[4]*kb.x + qh[5]*kb.y + qh[6]*kb.z + qh[7]*kb.w;
        s *= scale;
        m = fmaxf(m, s);
    }

    // pass 2: recompute scores, accumulate exp-sum and O
    float sum = 0.0f;
    float o[HD] = {};
    for (int g = 0; g < NH; ++g) {
        const float4 ka = k4[g * 2], kb = k4[g * 2 + 1];
        float s = qh[0]*ka.x + qh[1]*ka.y + qh[2]*ka.z + qh[3]*ka.w
                + qh[4]*kb.x + qh[5]*kb.y + qh[6]*kb.z + qh[7]*kb.w;
        s *= scale;
        const float e = __expf(s - m);
        sum += e;
        const float4 va = v4[g * 2], vb = v4[g * 2 + 1];
        o[0] += e * va.x; o[1] += e * va.y; o[2] += e * va.z; o[3] += e * va.w;
        o[4] += e * vb.x; o[5] += e * vb.y; o[6] += e * vb.z; o[7] += e * vb.w;
    }

    const float inv = 1.0f / sum;
    float4 oa, ob;
    oa.x = o[0]*inv; oa.y = o[1]*inv; oa.z = o[2]*inv; oa.w = o[3]*inv;
    ob.x = o[4]*inv; ob.y = o[5]*inv; ob.z = o[6]*inv; ob.w = o[7]*inv;
    float4* og = (float4*)(O + (size_t)t * DM + h * HD);
    og[0] = oa;
    og[1] = ob;
}

extern "C" void kernel_launch(void* const* d_in, const int* in_sizes, int n_in,
                              void* d_out, int out_size, void* d_ws, size_t ws_size,
                              hipStream_t stream)
{
    const float* x  = (const float*)d_in[0];
    // d_in[1] = phase_shift: analytically cancels (cos^2+sin^2), unused
    const float* Wq = (const float*)d_in[2];
    const float* bq = (const float*)d_in[3];
    const float* Wk = (const float*)d_in[4];
    const float* bk = (const float*)d_in[5];
    const float* Wv = (const float*)d_in[6];
    const float* bv = (const float*)d_in[7];
    const float* Wo = (const float*)d_in[8];
    const float* bo = (const float*)d_in[9];
    float* out = (float*)d_out;

    float* Q = (float*)d_ws;
    float* K = Q + (size_t)M_TOK * DM;
    float* V = K + (size_t)M_TOK * DM;
    float* O = V + (size_t)M_TOK * DM;

    const dim3 blk(256);

    // Q,K,V projections fused: grid.x = 3 * (2048/64) = 96
    gemm3<<<dim3(96, 16), blk, 0, stream>>>(x,
        Wq, bq, Q,
        Wk, bk, K,
        Wv, bv, V);

    attn<<<dim3(M_TOK), blk, 0, stream>>>(Q, K, V, O);

    // output projection: single GEMM, grid.x = 32
    gemm3<<<dim3(32, 16), blk, 0, stream>>>(O,
        Wo, bo, out,
        Wo, bo, out,
        Wo, bo, out);
}

// Round 2
// 246.775 us; speedup vs baseline: 2.6432x; 2.6432x over previous
//
#include <hip/hip_runtime.h>
#include <math.h>

#define M_TOK 1024   // B*S
#define DM    2048   // d_model
#define NH    256    // heads
#define HD    8      // head dim

typedef _Float16 f16x8 __attribute__((ext_vector_type(8)));
typedef _Float16 f16x4 __attribute__((ext_vector_type(4)));
typedef float    f32x4 __attribute__((ext_vector_type(4)));

// ---------------------------------------------------------------------------
// cast x: fp32 -> fp16, 8 elements/thread
__global__ __launch_bounds__(256) void cast_x(
    const float* __restrict__ in, _Float16* __restrict__ out, int n8)
{
    int i = blockIdx.x * blockDim.x + threadIdx.x;
    if (i >= n8) return;
    const float4 a = ((const float4*)in)[2 * i];
    const float4 b = ((const float4*)in)[2 * i + 1];
    f16x8 v;
    v[0] = (_Float16)a.x; v[1] = (_Float16)a.y; v[2] = (_Float16)a.z; v[3] = (_Float16)a.w;
    v[4] = (_Float16)b.x; v[5] = (_Float16)b.y; v[6] = (_Float16)b.z; v[7] = (_Float16)b.w;
    ((f16x8*)out)[i] = v;
}

// ---------------------------------------------------------------------------
// cast + transpose: W fp32 [k][n] (2048x2048) -> Wt fp16 [n][k]
// 64x64 tiles, scalar LDS ops with 65-stride padding (2-way conflicts = free)
__global__ __launch_bounds__(256) void castT(
    const float* __restrict__ W0, const float* __restrict__ W1,
    const float* __restrict__ W2, const float* __restrict__ W3,
    _Float16* __restrict__ T0, _Float16* __restrict__ T1,
    _Float16* __restrict__ T2, _Float16* __restrict__ T3)
{
    __shared__ float t[64][65];
    const int z = blockIdx.z;
    const float* W = (z == 0) ? W0 : (z == 1) ? W1 : (z == 2) ? W2 : W3;
    _Float16*    T = (z == 0) ? T0 : (z == 1) ? T1 : (z == 2) ? T2 : T3;

    const int nb = blockIdx.x * 64;   // n block
    const int kb = blockIdx.y * 64;   // k block
    const int tid = threadIdx.x;
    const int tr  = tid >> 4;          // 0..15
    const int tc  = (tid & 15) << 2;   // 0,4,...,60

    #pragma unroll
    for (int rr = 0; rr < 4; ++rr) {
        const int k = kb + rr * 16 + tr;
        const float4 v = *(const float4*)&W[(size_t)k * DM + nb + tc];
        t[rr * 16 + tr][tc + 0] = v.x;
        t[rr * 16 + tr][tc + 1] = v.y;
        t[rr * 16 + tr][tc + 2] = v.z;
        t[rr * 16 + tr][tc + 3] = v.w;
    }
    __syncthreads();
    #pragma unroll
    for (int rr = 0; rr < 4; ++rr) {
        const int n = nb + rr * 16 + tr;
        f16x4 v;
        #pragma unroll
        for (int j = 0; j < 4; ++j)
            v[j] = (_Float16)t[tc + j][rr * 16 + tr];
        *(f16x4*)&T[(size_t)n * DM + kb + tc] = v;
    }
}

// ---------------------------------------------------------------------------
// MFMA GEMM: C[M x 2048] = A[M x 2048](fp16) @ Bt^T + bias, C fp32.
// Bt is [2048][2048] fp16 with K contiguous (i.e., original W transposed).
// Tile 128x128, BK=32, 4 waves x (4x4) 16x16x32 MFMA tiles.
// grid.x = which*16 + colblock (fused triple), grid.y = rowblock.
__global__ __launch_bounds__(256) void gemm_mfma(
    const _Float16* __restrict__ A,
    const _Float16* __restrict__ Bt0, const float* __restrict__ b0, float* __restrict__ C0,
    const _Float16* __restrict__ Bt1, const float* __restrict__ b1, float* __restrict__ C1,
    const _Float16* __restrict__ Bt2, const float* __restrict__ b2, float* __restrict__ C2)
{
    __shared__ _Float16 As[128 * 32];   // 8 KB, row-major [m][k]
    __shared__ _Float16 Bs[128 * 32];   // 8 KB, row-major [n][k]

    const int which = blockIdx.x >> 4;
    const int bn    = (blockIdx.x & 15) * 128;
    const int bm    = blockIdx.y * 128;

    const _Float16* Bt   = (which == 0) ? Bt0 : (which == 1) ? Bt1 : Bt2;
    const float*    bias = (which == 0) ? b0  : (which == 1) ? b1  : b2;
    float*          C    = (which == 0) ? C0  : (which == 1) ? C1  : C2;

    const int tid  = threadIdx.x;
    const int lane = tid & 63;
    const int wv   = tid >> 6;          // 0..3
    const int wr   = (wv >> 1) * 64;    // wave row quadrant
    const int wc   = (wv & 1) * 64;     // wave col quadrant
    const int lr   = lane & 15;
    const int lk   = lane >> 4;         // 0..3

    // staging addresses: wave wv stages chunks 2wv, 2wv+1 (16 rows x 32 k each)
    const int ca0 = 2 * wv, ca1 = 2 * wv + 1;
    const _Float16* gA0 = A  + (size_t)(bm + ca0 * 16 + (lane >> 2)) * DM + (lane & 3) * 8;
    const _Float16* gA1 = A  + (size_t)(bm + ca1 * 16 + (lane >> 2)) * DM + (lane & 3) * 8;
    const _Float16* gB0 = Bt + (size_t)(bn + ca0 * 16 + (lane >> 2)) * DM + (lane & 3) * 8;
    const _Float16* gB1 = Bt + (size_t)(bn + ca1 * 16 + (lane >> 2)) * DM + (lane & 3) * 8;

    f32x4 acc[4][4] = {};

    for (int k0 = 0; k0 < DM; k0 += 32) {
        __syncthreads();   // previous iteration's fragment reads complete
        __builtin_amdgcn_global_load_lds(
            (const __attribute__((address_space(1))) void*)gA0,
            (__attribute__((address_space(3))) void*)&As[ca0 * 512], 16, 0, 0);
        __builtin_amdgcn_global_load_lds(
            (const __attribute__((address_space(1))) void*)gA1,
            (__attribute__((address_space(3))) void*)&As[ca1 * 512], 16, 0, 0);
        __builtin_amdgcn_global_load_lds(
            (const __attribute__((address_space(1))) void*)gB0,
            (__attribute__((address_space(3))) void*)&Bs[ca0 * 512], 16, 0, 0);
        __builtin_amdgcn_global_load_lds(
            (const __attribute__((address_space(1))) void*)gB1,
            (__attribute__((address_space(3))) void*)&Bs[ca1 * 512], 16, 0, 0);
        gA0 += 32; gA1 += 32; gB0 += 32; gB1 += 32;
        __syncthreads();   // staging drained (compiler emits vmcnt(0) before barrier)

        f16x8 aF[4], bF[4];
        #pragma unroll
        for (int i = 0; i < 4; ++i)
            aF[i] = *(const f16x8*)&As[(wr + i * 16 + lr) * 32 + lk * 8];
        #pragma unroll
        for (int j = 0; j < 4; ++j)
            bF[j] = *(const f16x8*)&Bs[(wc + j * 16 + lr) * 32 + lk * 8];

        #pragma unroll
        for (int i = 0; i < 4; ++i)
            #pragma unroll
            for (int j = 0; j < 4; ++j)
                acc[i][j] = __builtin_amdgcn_mfma_f32_16x16x32_f16(aF[i], bF[j], acc[i][j], 0, 0, 0);
    }

    // epilogue: C/D layout col = lane&15, row = (lane>>4)*4 + reg
    #pragma unroll
    for (int i = 0; i < 4; ++i) {
        #pragma unroll
        for (int j = 0; j < 4; ++j) {
            const int col = bn + wc + j * 16 + lr;
            const float bv = bias[col];
            #pragma unroll
            for (int r = 0; r < 4; ++r) {
                const int row = bm + wr + i * 16 + lk * 4 + r;
                C[(size_t)row * DM + col] = acc[i][j][r] + bv;
            }
        }
    }
}

// ---------------------------------------------------------------------------
// Per-token head-mixing attention, single-pass softmax (no max shift: |s|<~6,
// exp safe in fp32; softmax is shift-invariant). O emitted in fp16.
__global__ __launch_bounds__(256) void attn(
    const float* __restrict__ Q, const float* __restrict__ K,
    const float* __restrict__ V, _Float16* __restrict__ O)
{
    __shared__ float qs[DM];
    __shared__ float ks[DM];
    __shared__ float vs[DM];

    const int t = blockIdx.x;
    const int h = threadIdx.x;

    {
        const float4* qg = (const float4*)(Q + (size_t)t * DM);
        const float4* kg = (const float4*)(K + (size_t)t * DM);
        const float4* vg = (const float4*)(V + (size_t)t * DM);
        float4* q4 = (float4*)qs; float4* k4 = (float4*)ks; float4* v4 = (float4*)vs;
        q4[h] = qg[h]; q4[h + 256] = qg[h + 256];
        k4[h] = kg[h]; k4[h + 256] = kg[h + 256];
        v4[h] = vg[h]; v4[h + 256] = vg[h + 256];
    }
    __syncthreads();

    float qh[HD];
    #pragma unroll
    for (int d = 0; d < HD; ++d) qh[d] = qs[h * HD + d];

    const float scale = 0.35355339059327373f;   // 1/sqrt(8)
    const float4* k4 = (const float4*)ks;
    const float4* v4 = (const float4*)vs;

    float sum = 0.0f;
    float o[HD] = {};
    for (int g = 0; g < NH; ++g) {
        const float4 ka = k4[g * 2], kb = k4[g * 2 + 1];   // broadcast LDS reads (free)
        float s = qh[0]*ka.x + qh[1]*ka.y + qh[2]*ka.z + qh[3]*ka.w
                + qh[4]*kb.x + qh[5]*kb.y + qh[6]*kb.z + qh[7]*kb.w;
        const float e = __expf(s * scale);
        sum += e;
        const float4 va = v4[g * 2], vb = v4[g * 2 + 1];
        o[0] += e * va.x; o[1] += e * va.y; o[2] += e * va.z; o[3] += e * va.w;
        o[4] += e * vb.x; o[5] += e * vb.y; o[6] += e * vb.z; o[7] += e * vb.w;
    }

    const float inv = 1.0f / sum;
    f16x8 ov;
    #pragma unroll
    for (int d = 0; d < HD; ++d) ov[d] = (_Float16)(o[d] * inv);
    *(f16x8*)&O[(size_t)t * DM + h * HD] = ov;
}

// ---------------------------------------------------------------------------
extern "C" void kernel_launch(void* const* d_in, const int* in_sizes, int n_in,
                              void* d_out, int out_size, void* d_ws, size_t ws_size,
                              hipStream_t stream)
{
    const float* x  = (const float*)d_in[0];
    // d_in[1] = phase_shift: cancels analytically (cos^2 + sin^2 = 1), unused
    const float* Wq = (const float*)d_in[2];
    const float* bq = (const float*)d_in[3];
    const float* Wk = (const float*)d_in[4];
    const float* bk = (const float*)d_in[5];
    const float* Wv = (const float*)d_in[6];
    const float* bv = (const float*)d_in[7];
    const float* Wo = (const float*)d_in[8];
    const float* bo = (const float*)d_in[9];
    float* out = (float*)d_out;

    // workspace layout (64 MB total)
    char* ws = (char*)d_ws;
    _Float16* xh  = (_Float16*)(ws);                         // 4 MB
    _Float16* Wtq = (_Float16*)(ws + (4u << 20));            // 8 MB
    _Float16* Wtk = (_Float16*)(ws + (12u << 20));           // 8 MB
    _Float16* Wtv = (_Float16*)(ws + (20u << 20));           // 8 MB
    _Float16* Wto = (_Float16*)(ws + (28u << 20));           // 8 MB
    float*    Q   = (float*)   (ws + (36u << 20));           // 8 MB
    float*    K   = (float*)   (ws + (44u << 20));           // 8 MB
    float*    V   = (float*)   (ws + (52u << 20));           // 8 MB
    _Float16* Oh  = (_Float16*)(ws + (60u << 20));           // 4 MB

    const dim3 blk(256);

    cast_x<<<dim3((M_TOK * DM / 8 + 255) / 256), blk, 0, stream>>>(x, xh, M_TOK * DM / 8);

    castT<<<dim3(32, 32, 4), blk, 0, stream>>>(Wq, Wk, Wv, Wo, Wtq, Wtk, Wtv, Wto);

    // QKV fused: grid.x = 3*16
    gemm_mfma<<<dim3(48, 8), blk, 0, stream>>>(xh,
        Wtq, bq, Q,
        Wtk, bk, K,
        Wtv, bv, V);

    attn<<<dim3(M_TOK), blk, 0, stream>>>(Q, K, V, Oh);

    // output projection
    gemm_mfma<<<dim3(16, 8), blk, 0, stream>>>(Oh,
        Wto, bo, out,
        Wto, bo, out,
        Wto, bo, out);
}

// Round 3
// 222.555 us; speedup vs baseline: 2.9309x; 1.1088x over previous
//
#include <hip/hip_runtime.h>
#include <math.h>

#define M_TOK 1024   // B*S
#define DM    2048   // d_model
#define NH    256    // heads
#define HD    8      // head dim
#define SCALE 0.35355339059327373f   // 1/sqrt(8)

typedef _Float16 f16x8 __attribute__((ext_vector_type(8)));
typedef _Float16 f16x4 __attribute__((ext_vector_type(4)));
typedef float    f32x4 __attribute__((ext_vector_type(4)));

// ---------------------------------------------------------------------------
// cast x: fp32 -> fp16, 8 elements/thread
__global__ __launch_bounds__(256) void cast_x(
    const float* __restrict__ in, _Float16* __restrict__ out, int n8)
{
    int i = blockIdx.x * blockDim.x + threadIdx.x;
    if (i >= n8) return;
    const float4 a = ((const float4*)in)[2 * i];
    const float4 b = ((const float4*)in)[2 * i + 1];
    f16x8 v;
    v[0] = (_Float16)a.x; v[1] = (_Float16)a.y; v[2] = (_Float16)a.z; v[3] = (_Float16)a.w;
    v[4] = (_Float16)b.x; v[5] = (_Float16)b.y; v[6] = (_Float16)b.z; v[7] = (_Float16)b.w;
    ((f16x8*)out)[i] = v;
}

// ---------------------------------------------------------------------------
// cast + transpose: W fp32 [k][n] (2048x2048) -> Wt fp16 [n][k]
__global__ __launch_bounds__(256) void castT(
    const float* __restrict__ W0, const float* __restrict__ W1,
    const float* __restrict__ W2, const float* __restrict__ W3,
    _Float16* __restrict__ T0, _Float16* __restrict__ T1,
    _Float16* __restrict__ T2, _Float16* __restrict__ T3)
{
    __shared__ float t[64][65];
    const int z = blockIdx.z;
    const float* W = (z == 0) ? W0 : (z == 1) ? W1 : (z == 2) ? W2 : W3;
    _Float16*    T = (z == 0) ? T0 : (z == 1) ? T1 : (z == 2) ? T2 : T3;

    const int nb = blockIdx.x * 64;
    const int kb = blockIdx.y * 64;
    const int tid = threadIdx.x;
    const int tr  = tid >> 4;
    const int tc  = (tid & 15) << 2;

    #pragma unroll
    for (int rr = 0; rr < 4; ++rr) {
        const int k = kb + rr * 16 + tr;
        const float4 v = *(const float4*)&W[(size_t)k * DM + nb + tc];
        t[rr * 16 + tr][tc + 0] = v.x;
        t[rr * 16 + tr][tc + 1] = v.y;
        t[rr * 16 + tr][tc + 2] = v.z;
        t[rr * 16 + tr][tc + 3] = v.w;
    }
    __syncthreads();
    #pragma unroll
    for (int rr = 0; rr < 4; ++rr) {
        const int n = nb + rr * 16 + tr;
        f16x4 v;
        #pragma unroll
        for (int j = 0; j < 4; ++j)
            v[j] = (_Float16)t[tc + j][rr * 16 + tr];
        *(f16x4*)&T[(size_t)n * DM + kb + tc] = v;
    }
}

// ---------------------------------------------------------------------------
// MFMA GEMM: C[M x 2048] = A(fp16) @ Bt^T + bias.
// Tile (32*TI) x 128, BK=32, 4 waves in 2x2, each TI x 4 MFMA tiles.
// F16OUT: emit _Float16 (bias still added in fp32), else fp32.
// grid.x = which*16 + colblock (fused triple), grid.y = rowblock.
template<int TI, bool F16OUT>
__global__ __launch_bounds__(256) void gemm_t(
    const _Float16* __restrict__ A,
    const _Float16* __restrict__ Bt0, const float* __restrict__ b0, void* __restrict__ C0,
    const _Float16* __restrict__ Bt1, const float* __restrict__ b1, void* __restrict__ C1,
    const _Float16* __restrict__ Bt2, const float* __restrict__ b2, void* __restrict__ C2)
{
    constexpr int BM = 32 * TI;
    constexpr int NA = 2 * TI;          // A chunks of 16 rows
    constexpr int NB = 8;               // B chunks
    constexpr int PC = (NA + NB) / 4;   // chunks per wave

    __shared__ _Float16 As[BM * 32];
    __shared__ _Float16 Bs[128 * 32];

    const int which = blockIdx.x >> 4;
    const int bn    = (blockIdx.x & 15) * 128;
    const int bm    = blockIdx.y * BM;

    const _Float16* Bt   = (which == 0) ? Bt0 : (which == 1) ? Bt1 : Bt2;
    const float*    bias = (which == 0) ? b0  : (which == 1) ? b1  : b2;
    void*           C    = (which == 0) ? C0  : (which == 1) ? C1  : C2;

    const int tid  = threadIdx.x;
    const int lane = tid & 63;
    const int wv   = tid >> 6;
    const int wr   = (wv >> 1) * 16 * TI;
    const int wc   = (wv & 1) * 64;
    const int lr   = lane & 15;
    const int lk   = lane >> 4;

    const _Float16* gsrc[PC];
    _Float16*       ldst[PC];
    #pragma unroll
    for (int p = 0; p < PC; ++p) {
        const int c = wv * PC + p;
        if (c < NA) {
            ldst[p] = &As[c * 512];
            gsrc[p] = A + (size_t)(bm + c * 16 + (lane >> 2)) * DM + (lane & 3) * 8;
        } else {
            ldst[p] = &Bs[(c - NA) * 512];
            gsrc[p] = Bt + (size_t)(bn + (c - NA) * 16 + (lane >> 2)) * DM + (lane & 3) * 8;
        }
    }

    f32x4 acc[TI][4] = {};

    for (int k0 = 0; k0 < DM; k0 += 32) {
        __syncthreads();
        #pragma unroll
        for (int p = 0; p < PC; ++p) {
            __builtin_amdgcn_global_load_lds(
                (const __attribute__((address_space(1))) void*)gsrc[p],
                (__attribute__((address_space(3))) void*)ldst[p], 16, 0, 0);
            gsrc[p] += 32;
        }
        __syncthreads();

        f16x8 aF[TI], bF[4];
        #pragma unroll
        for (int i = 0; i < TI; ++i)
            aF[i] = *(const f16x8*)&As[(wr + i * 16 + lr) * 32 + lk * 8];
        #pragma unroll
        for (int j = 0; j < 4; ++j)
            bF[j] = *(const f16x8*)&Bs[(wc + j * 16 + lr) * 32 + lk * 8];

        #pragma unroll
        for (int i = 0; i < TI; ++i)
            #pragma unroll
            for (int j = 0; j < 4; ++j)
                acc[i][j] = __builtin_amdgcn_mfma_f32_16x16x32_f16(aF[i], bF[j], acc[i][j], 0, 0, 0);
    }

    #pragma unroll
    for (int i = 0; i < TI; ++i) {
        #pragma unroll
        for (int j = 0; j < 4; ++j) {
            const int col = bn + wc + j * 16 + lr;
            const float bv = bias[col];
            #pragma unroll
            for (int r = 0; r < 4; ++r) {
                const int row = bm + wr + i * 16 + lk * 4 + r;
                const float v = acc[i][j][r] + bv;
                if (F16OUT)
                    ((_Float16*)C)[(size_t)row * DM + col] = (_Float16)v;
                else
                    ((float*)C)[(size_t)row * DM + col] = v;
            }
        }
    }
}

// ---------------------------------------------------------------------------
// MFMA attention: one block per token, 4 waves, wave wv owns heads
// [64wv, 64wv+64). S^T = K.Q^T via mfma (K=8 zero-padded), exp in fp32,
// pack to fp16 in LDS (wave-private region, no barrier), O = A.V via mfma.
__global__ __launch_bounds__(256) void attn_mfma(
    const _Float16* __restrict__ Qh, const _Float16* __restrict__ Kh,
    const _Float16* __restrict__ Vh, _Float16* __restrict__ Oh)
{
    __shared__ _Float16 Vt[8][264];      // V transposed [d][g], padded
    __shared__ _Float16 Al[256][72];     // exp(S) [h][g-chunk 64], padded (36 KB)
    __shared__ _Float16 Ot[256][8];      // O bounce [h][d]

    const int t    = blockIdx.x;
    const int tid  = threadIdx.x;
    const int lane = tid & 63;
    const int wv   = tid >> 6;
    const int col  = lane & 15;
    const int quad = lane >> 4;
    const int hbase = wv * 64;

    const _Float16* qb = Qh + (size_t)t * DM;
    const _Float16* kb = Kh + (size_t)t * DM;
    const _Float16* vb = Vh + (size_t)t * DM;

    // stage V transposed: thread g=tid reads V[g][0..7]
    {
        const f16x8 v = *(const f16x8*)(vb + tid * 8);
        #pragma unroll
        for (int d = 0; d < 8; ++d) Vt[d][tid] = v[d];
    }

    // Q B-fragments for this wave's 4 h-tiles (quad 0 holds d=0..7, rest zero),
    // prescaled by 1/sqrt(8)
    f16x8 qf[4];
    #pragma unroll
    for (int ht = 0; ht < 4; ++ht) {
        f16x8 v = {};
        if (quad == 0)
            v = *(const f16x8*)(qb + (hbase + ht * 16 + col) * 8);
        #pragma unroll
        for (int j = 0; j < 8; ++j) qf[ht][j] = v[j] * (_Float16)SCALE;
    }

    __syncthreads();   // Vt visible to all waves

    const f32x4 zf = {};
    float rsum[4] = {};
    f32x4 oacc[4] = {};

    #pragma unroll 1
    for (int c = 0; c < 4; ++c) {
        const int gchunk = c * 64;

        // K A-fragments for this chunk's 4 g-tiles
        f16x8 kf[4];
        #pragma unroll
        for (int gt = 0; gt < 4; ++gt) {
            f16x8 v = {};
            if (quad == 0)
                v = *(const f16x8*)(kb + (gchunk + gt * 16 + col) * 8);
            kf[gt] = v;
        }

        // S^T tiles: D(g_local, h_local)
        f32x4 s[4][4];
        #pragma unroll
        for (int gt = 0; gt < 4; ++gt)
            #pragma unroll
            for (int ht = 0; ht < 4; ++ht)
                s[gt][ht] = __builtin_amdgcn_mfma_f32_16x16x32_f16(kf[gt], qf[ht], zf, 0, 0, 0);

        // exp -> fp16, pack 4 rows (consecutive g) -> one ds_write_b64;
        // rowsum from the fp16-rounded values (matches what O-mfma consumes)
        #pragma unroll
        for (int gt = 0; gt < 4; ++gt) {
            #pragma unroll
            for (int ht = 0; ht < 4; ++ht) {
                f16x4 e4;
                #pragma unroll
                for (int r = 0; r < 4; ++r) {
                    e4[r] = (_Float16)__expf(s[gt][ht][r]);
                    rsum[ht] += (float)e4[r];
                }
                *(f16x4*)&Al[hbase + ht * 16 + col][gt * 16 + quad * 4] = e4;
            }
        }

        // O += A_chunk . V_chunk  (2 k-steps of 32)
        #pragma unroll
        for (int ks = 0; ks < 2; ++ks) {
            f16x8 vf = {};
            if (col < 8)
                vf = *(const f16x8*)&Vt[col][gchunk + ks * 32 + quad * 8];
            #pragma unroll
            for (int ht = 0; ht < 4; ++ht) {
                const f16x8 af = *(const f16x8*)&Al[hbase + ht * 16 + col][ks * 32 + quad * 8];
                oacc[ht] = __builtin_amdgcn_mfma_f32_16x16x32_f16(af, vf, oacc[ht], 0, 0, 0);
            }
        }
    }

    // total row sums: butterfly across quads (lanes sharing col)
    #pragma unroll
    for (int ht = 0; ht < 4; ++ht) {
        rsum[ht] += __shfl_xor(rsum[ht], 16, 64);
        rsum[ht] += __shfl_xor(rsum[ht], 32, 64);
    }

    // normalize + bounce O through LDS (wave-private rows), coalesced store
    #pragma unroll
    for (int ht = 0; ht < 4; ++ht) {
        #pragma unroll
        for (int r = 0; r < 4; ++r) {
            const float sh = __shfl(rsum[ht], quad * 4 + r, 64);
            const float v  = oacc[ht][r] / sh;
            if (col < 8)
                Ot[hbase + ht * 16 + quad * 4 + r][col] = (_Float16)v;
        }
    }
    const f16x8 ov = *(const f16x8*)&Ot[tid][0];
    *(f16x8*)(Oh + (size_t)t * DM + tid * 8) = ov;
}

// ---------------------------------------------------------------------------
extern "C" void kernel_launch(void* const* d_in, const int* in_sizes, int n_in,
                              void* d_out, int out_size, void* d_ws, size_t ws_size,
                              hipStream_t stream)
{
    const float* x  = (const float*)d_in[0];
    // d_in[1] = phase_shift: cancels analytically (cos^2 + sin^2 = 1), unused
    const float* Wq = (const float*)d_in[2];
    const float* bq = (const float*)d_in[3];
    const float* Wk = (const float*)d_in[4];
    const float* bk = (const float*)d_in[5];
    const float* Wv = (const float*)d_in[6];
    const float* bv = (const float*)d_in[7];
    const float* Wo = (const float*)d_in[8];
    const float* bo = (const float*)d_in[9];
    float* out = (float*)d_out;

    char* ws = (char*)d_ws;
    _Float16* xh  = (_Float16*)(ws);                 // 4 MB
    _Float16* Wtq = (_Float16*)(ws + (4u  << 20));   // 8 MB
    _Float16* Wtk = (_Float16*)(ws + (12u << 20));   // 8 MB
    _Float16* Wtv = (_Float16*)(ws + (20u << 20));   // 8 MB
    _Float16* Wto = (_Float16*)(ws + (28u << 20));   // 8 MB
    _Float16* Qh  = (_Float16*)(ws + (36u << 20));   // 4 MB
    _Float16* Kh  = (_Float16*)(ws + (40u << 20));   // 4 MB
    _Float16* Vh  = (_Float16*)(ws + (44u << 20));   // 4 MB
    _Float16* Oh  = (_Float16*)(ws + (48u << 20));   // 4 MB

    const dim3 blk(256);

    cast_x<<<dim3((M_TOK * DM / 8 + 255) / 256), blk, 0, stream>>>(x, xh, M_TOK * DM / 8);

    castT<<<dim3(32, 32, 4), blk, 0, stream>>>(Wq, Wk, Wv, Wo, Wtq, Wtk, Wtv, Wto);

    // QKV fused, 128x128 tiles, fp16 out: grid 48 x 8
    gemm_t<4, true><<<dim3(48, 8), blk, 0, stream>>>(xh,
        Wtq, bq, (void*)Qh,
        Wtk, bk, (void*)Kh,
        Wtv, bv, (void*)Vh);

    attn_mfma<<<dim3(M_TOK), blk, 0, stream>>>(Qh, Kh, Vh, Oh);

    // output projection, 64x128 tiles (256 blocks), fp32 out: grid 16 x 16
    gemm_t<2, false><<<dim3(16, 16), blk, 0, stream>>>(Oh,
        Wto, bo, (void*)out,
        Wto, bo, (void*)out,
        Wto, bo, (void*)out);
}

// Round 4
// 222.063 us; speedup vs baseline: 2.9374x; 1.0022x over previous
//
#include <hip/hip_runtime.h>
#include <math.h>

#define M_TOK 1024   // B*S
#define DM    2048   // d_model
#define NH    256    // heads
#define HD    8      // head dim
#define SCALE 0.35355339059327373f   // 1/sqrt(8)

typedef _Float16 f16x8 __attribute__((ext_vector_type(8)));
typedef _Float16 f16x4 __attribute__((ext_vector_type(4)));
typedef float    f32x4 __attribute__((ext_vector_type(4)));

// ---------------------------------------------------------------------------
// prep: z<4 -> weight fp32 [k][n] -> fp16 [n][k] (cast+transpose, 64x64 tiles);
//       z==4 -> x fp32 -> fp16 straight cast (8 elem/thread)
__global__ __launch_bounds__(256) void prep(
    const float* __restrict__ x, _Float16* __restrict__ xh,
    const float* __restrict__ W0, const float* __restrict__ W1,
    const float* __restrict__ W2, const float* __restrict__ W3,
    _Float16* __restrict__ T0, _Float16* __restrict__ T1,
    _Float16* __restrict__ T2, _Float16* __restrict__ T3)
{
    __shared__ float t[64][65];
    const int tid = threadIdx.x;
    const int z   = blockIdx.z;

    if (z == 4) {   // cast x
        const int i = (blockIdx.y * 32 + blockIdx.x) * 256 + tid;   // < 262144
        const float4 a = ((const float4*)x)[2 * i];
        const float4 b = ((const float4*)x)[2 * i + 1];
        f16x8 v;
        v[0] = (_Float16)a.x; v[1] = (_Float16)a.y; v[2] = (_Float16)a.z; v[3] = (_Float16)a.w;
        v[4] = (_Float16)b.x; v[5] = (_Float16)b.y; v[6] = (_Float16)b.z; v[7] = (_Float16)b.w;
        ((f16x8*)xh)[i] = v;
        return;
    }

    const float* W = (z == 0) ? W0 : (z == 1) ? W1 : (z == 2) ? W2 : W3;
    _Float16*    T = (z == 0) ? T0 : (z == 1) ? T1 : (z == 2) ? T2 : T3;

    const int nb = blockIdx.x * 64;
    const int kb = blockIdx.y * 64;
    const int tr = tid >> 4;
    const int tc = (tid & 15) << 2;

    #pragma unroll
    for (int rr = 0; rr < 4; ++rr) {
        const int k = kb + rr * 16 + tr;
        const float4 v = *(const float4*)&W[(size_t)k * DM + nb + tc];
        t[rr * 16 + tr][tc + 0] = v.x;
        t[rr * 16 + tr][tc + 1] = v.y;
        t[rr * 16 + tr][tc + 2] = v.z;
        t[rr * 16 + tr][tc + 3] = v.w;
    }
    __syncthreads();
    #pragma unroll
    for (int rr = 0; rr < 4; ++rr) {
        const int n = nb + rr * 16 + tr;
        f16x4 v;
        #pragma unroll
        for (int j = 0; j < 4; ++j)
            v[j] = (_Float16)t[tc + j][rr * 16 + tr];
        *(f16x4*)&T[(size_t)n * DM + kb + tc] = v;
    }
}

// ---------------------------------------------------------------------------
// MFMA GEMM, 512 threads = 8 waves in a 2x4 grid; each wave TI x 2 MFMA tiles.
// Tile (32*TI) x 128, BK=32. C = A(fp16) @ Bt^T + bias.
// grid.x = which*16 + colblock (fused triple), grid.y = rowblock.
template<int TI, bool F16OUT>
__global__ __launch_bounds__(512) void gemm_t(
    const _Float16* __restrict__ A,
    const _Float16* __restrict__ Bt0, const float* __restrict__ b0, void* __restrict__ C0,
    const _Float16* __restrict__ Bt1, const float* __restrict__ b1, void* __restrict__ C1,
    const _Float16* __restrict__ Bt2, const float* __restrict__ b2, void* __restrict__ C2)
{
    constexpr int BM = 32 * TI;         // 2 wave-rows * TI * 16
    constexpr int NA = 2 * TI;          // A chunks (16 rows x 32 k each)
    constexpr int NB = 8;               // B chunks
    constexpr int NC = NA + NB;
    constexpr int PC = (NC + 7) / 8;    // staging rounds per wave

    __shared__ _Float16 As[BM * 32];
    __shared__ _Float16 Bs[128 * 32];

    const int which = blockIdx.x >> 4;
    const int bn    = (blockIdx.x & 15) * 128;
    const int bm    = blockIdx.y * BM;

    const _Float16* Bt   = (which == 0) ? Bt0 : (which == 1) ? Bt1 : Bt2;
    const float*    bias = (which == 0) ? b0  : (which == 1) ? b1  : b2;
    void*           C    = (which == 0) ? C0  : (which == 1) ? C1  : C2;

    const int tid  = threadIdx.x;
    const int lane = tid & 63;
    const int wv   = tid >> 6;          // 0..7
    const int wr   = (wv >> 2) * (16 * TI);   // 2 wave-rows
    const int wc   = (wv & 3) * 32;           // 4 wave-cols
    const int lr   = lane & 15;
    const int lk   = lane >> 4;

    // round-robin staging: round p, wave wv handles chunk c = p*8 + wv
    bool            vld[PC];
    const _Float16* gsrc[PC];
    _Float16*       ldst[PC];
    #pragma unroll
    for (int p = 0; p < PC; ++p) {
        const int c = p * 8 + wv;
        vld[p] = (c < NC);
        if (c < NA) {
            ldst[p] = &As[c * 512];
            gsrc[p] = A + (size_t)(bm + c * 16 + (lane >> 2)) * DM + (lane & 3) * 8;
        } else if (c < NC) {
            ldst[p] = &Bs[(c - NA) * 512];
            gsrc[p] = Bt + (size_t)(bn + (c - NA) * 16 + (lane >> 2)) * DM + (lane & 3) * 8;
        } else {
            ldst[p] = &As[0];
            gsrc[p] = A;
        }
    }

    f32x4 acc[TI][2] = {};

    for (int k0 = 0; k0 < DM; k0 += 32) {
        __syncthreads();
        #pragma unroll
        for (int p = 0; p < PC; ++p) {
            if (vld[p])
                __builtin_amdgcn_global_load_lds(
                    (const __attribute__((address_space(1))) void*)gsrc[p],
                    (__attribute__((address_space(3))) void*)ldst[p], 16, 0, 0);
            gsrc[p] += 32;
        }
        __syncthreads();

        f16x8 aF[TI], bF[2];
        #pragma unroll
        for (int i = 0; i < TI; ++i)
            aF[i] = *(const f16x8*)&As[(wr + i * 16 + lr) * 32 + lk * 8];
        #pragma unroll
        for (int j = 0; j < 2; ++j)
            bF[j] = *(const f16x8*)&Bs[(wc + j * 16 + lr) * 32 + lk * 8];

        #pragma unroll
        for (int i = 0; i < TI; ++i)
            #pragma unroll
            for (int j = 0; j < 2; ++j)
                acc[i][j] = __builtin_amdgcn_mfma_f32_16x16x32_f16(aF[i], bF[j], acc[i][j], 0, 0, 0);
    }

    #pragma unroll
    for (int i = 0; i < TI; ++i) {
        #pragma unroll
        for (int j = 0; j < 2; ++j) {
            const int col = bn + wc + j * 16 + lr;
            const float bv = bias[col];
            #pragma unroll
            for (int r = 0; r < 4; ++r) {
                const int row = bm + wr + i * 16 + lk * 4 + r;
                const float v = acc[i][j][r] + bv;
                if (F16OUT)
                    ((_Float16*)C)[(size_t)row * DM + col] = (_Float16)v;
                else
                    ((float*)C)[(size_t)row * DM + col] = v;
            }
        }
    }
}

// ---------------------------------------------------------------------------
// MFMA attention: one block per token, 4 waves, wave wv owns heads
// [64wv, 64wv+64). S^T = K.Q^T via mfma (K=8 zero-padded), exp in fp32,
// pack to fp16 in LDS (wave-private region, no barrier), O = A.V via mfma.
__global__ __launch_bounds__(256) void attn_mfma(
    const _Float16* __restrict__ Qh, const _Float16* __restrict__ Kh,
    const _Float16* __restrict__ Vh, _Float16* __restrict__ Oh)
{
    __shared__ _Float16 Vt[8][264];      // V transposed [d][g], padded
    __shared__ _Float16 Al[256][72];     // exp(S) [h][g-chunk 64], padded (36 KB)
    __shared__ _Float16 Ot[256][8];      // O bounce [h][d]

    const int t    = blockIdx.x;
    const int tid  = threadIdx.x;
    const int lane = tid & 63;
    const int wv   = tid >> 6;
    const int col  = lane & 15;
    const int quad = lane >> 4;
    const int hbase = wv * 64;

    const _Float16* qb = Qh + (size_t)t * DM;
    const _Float16* kb = Kh + (size_t)t * DM;
    const _Float16* vb = Vh + (size_t)t * DM;

    // stage V transposed: thread g=tid reads V[g][0..7]
    {
        const f16x8 v = *(const f16x8*)(vb + tid * 8);
        #pragma unroll
        for (int d = 0; d < 8; ++d) Vt[d][tid] = v[d];
    }

    // Q B-fragments (quad 0 holds d=0..7, rest zero), prescaled by 1/sqrt(8)
    f16x8 qf[4];
    #pragma unroll
    for (int ht = 0; ht < 4; ++ht) {
        f16x8 v = {};
        if (quad == 0)
            v = *(const f16x8*)(qb + (hbase + ht * 16 + col) * 8);
        #pragma unroll
        for (int j = 0; j < 8; ++j) qf[ht][j] = v[j] * (_Float16)SCALE;
    }

    __syncthreads();   // Vt visible to all waves

    const f32x4 zf = {};
    float rsum[4] = {};
    f32x4 oacc[4] = {};

    #pragma unroll 1
    for (int c = 0; c < 4; ++c) {
        const int gchunk = c * 64;

        f16x8 kf[4];
        #pragma unroll
        for (int gt = 0; gt < 4; ++gt) {
            f16x8 v = {};
            if (quad == 0)
                v = *(const f16x8*)(kb + (gchunk + gt * 16 + col) * 8);
            kf[gt] = v;
        }

        f32x4 s[4][4];
        #pragma unroll
        for (int gt = 0; gt < 4; ++gt)
            #pragma unroll
            for (int ht = 0; ht < 4; ++ht)
                s[gt][ht] = __builtin_amdgcn_mfma_f32_16x16x32_f16(kf[gt], qf[ht], zf, 0, 0, 0);

        #pragma unroll
        for (int gt = 0; gt < 4; ++gt) {
            #pragma unroll
            for (int ht = 0; ht < 4; ++ht) {
                f16x4 e4;
                #pragma unroll
                for (int r = 0; r < 4; ++r) {
                    e4[r] = (_Float16)__expf(s[gt][ht][r]);
                    rsum[ht] += (float)e4[r];
                }
                *(f16x4*)&Al[hbase + ht * 16 + col][gt * 16 + quad * 4] = e4;
            }
        }

        #pragma unroll
        for (int ks = 0; ks < 2; ++ks) {
            f16x8 vf = {};
            if (col < 8)
                vf = *(const f16x8*)&Vt[col][gchunk + ks * 32 + quad * 8];
            #pragma unroll
            for (int ht = 0; ht < 4; ++ht) {
                const f16x8 af = *(const f16x8*)&Al[hbase + ht * 16 + col][ks * 32 + quad * 8];
                oacc[ht] = __builtin_amdgcn_mfma_f32_16x16x32_f16(af, vf, oacc[ht], 0, 0, 0);
            }
        }
    }

    #pragma unroll
    for (int ht = 0; ht < 4; ++ht) {
        rsum[ht] += __shfl_xor(rsum[ht], 16, 64);
        rsum[ht] += __shfl_xor(rsum[ht], 32, 64);
    }

    #pragma unroll
    for (int ht = 0; ht < 4; ++ht) {
        #pragma unroll
        for (int r = 0; r < 4; ++r) {
            const float sh = __shfl(rsum[ht], quad * 4 + r, 64);
            const float v  = oacc[ht][r] / sh;
            if (col < 8)
                Ot[hbase + ht * 16 + quad * 4 + r][col] = (_Float16)v;
        }
    }
    const f16x8 ov = *(const f16x8*)&Ot[tid][0];
    *(f16x8*)(Oh + (size_t)t * DM + tid * 8) = ov;
}

// ---------------------------------------------------------------------------
extern "C" void kernel_launch(void* const* d_in, const int* in_sizes, int n_in,
                              void* d_out, int out_size, void* d_ws, size_t ws_size,
                              hipStream_t stream)
{
    const float* x  = (const float*)d_in[0];
    // d_in[1] = phase_shift: cancels analytically (cos^2 + sin^2 = 1), unused
    const float* Wq = (const float*)d_in[2];
    const float* bq = (const float*)d_in[3];
    const float* Wk = (const float*)d_in[4];
    const float* bk = (const float*)d_in[5];
    const float* Wv = (const float*)d_in[6];
    const float* bv = (const float*)d_in[7];
    const float* Wo = (const float*)d_in[8];
    const float* bo = (const float*)d_in[9];
    float* out = (float*)d_out;

    char* ws = (char*)d_ws;
    _Float16* xh  = (_Float16*)(ws);                 // 4 MB
    _Float16* Wtq = (_Float16*)(ws + (4u  << 20));   // 8 MB
    _Float16* Wtk = (_Float16*)(ws + (12u << 20));   // 8 MB
    _Float16* Wtv = (_Float16*)(ws + (20u << 20));   // 8 MB
    _Float16* Wto = (_Float16*)(ws + (28u << 20));   // 8 MB
    _Float16* Qh  = (_Float16*)(ws + (36u << 20));   // 4 MB
    _Float16* Kh  = (_Float16*)(ws + (40u << 20));   // 4 MB
    _Float16* Vh  = (_Float16*)(ws + (44u << 20));   // 4 MB
    _Float16* Oh  = (_Float16*)(ws + (48u << 20));   // 4 MB

    // cast x + cast/transpose 4 weights in one launch
    prep<<<dim3(32, 32, 5), dim3(256), 0, stream>>>(
        x, xh, Wq, Wk, Wv, Wo, Wtq, Wtk, Wtv, Wto);

    // QKV fused, 128x128 tiles, 8 waves/block, fp16 out: 384 blocks, 3072 waves
    gemm_t<4, true><<<dim3(48, 8), dim3(512), 0, stream>>>(xh,
        Wtq, bq, (void*)Qh,
        Wtk, bk, (void*)Kh,
        Wtv, bv, (void*)Vh);

    attn_mfma<<<dim3(M_TOK), dim3(256), 0, stream>>>(Qh, Kh, Vh, Oh);

    // output projection, 64x128 tiles, 8 waves/block, fp32 out: 256 blocks
    gemm_t<2, false><<<dim3(16, 16), dim3(512), 0, stream>>>(Oh,
        Wto, bo, (void*)out,
        Wto, bo, (void*)out,
        Wto, bo, (void*)out);
}

// Round 5
// 201.107 us; speedup vs baseline: 3.2434x; 1.1042x over previous
//
#include <hip/hip_runtime.h>
#include <math.h>

#define M_TOK 1024   // B*S
#define DM    2048   // d_model
#define NH    256    // heads
#define HD    8      // head dim
#define SCALE 0.35355339059327373f   // 1/sqrt(8)

typedef _Float16 f16x8 __attribute__((ext_vector_type(8)));
typedef _Float16 f16x4 __attribute__((ext_vector_type(4)));
typedef float    f32x4 __attribute__((ext_vector_type(4)));

// ---------------------------------------------------------------------------
// prep: z<4 -> weight fp32 [k][n] -> fp16 [n][k] (cast+transpose, 64x64 tiles);
//       z==4 -> x fp32 -> fp16 straight cast (8 elem/thread)
__global__ __launch_bounds__(256) void prep(
    const float* __restrict__ x, _Float16* __restrict__ xh,
    const float* __restrict__ W0, const float* __restrict__ W1,
    const float* __restrict__ W2, const float* __restrict__ W3,
    _Float16* __restrict__ T0, _Float16* __restrict__ T1,
    _Float16* __restrict__ T2, _Float16* __restrict__ T3)
{
    __shared__ float t[64][65];
    const int tid = threadIdx.x;
    const int z   = blockIdx.z;

    if (z == 4) {   // cast x
        const int i = (blockIdx.y * 32 + blockIdx.x) * 256 + tid;   // < 262144
        const float4 a = ((const float4*)x)[2 * i];
        const float4 b = ((const float4*)x)[2 * i + 1];
        f16x8 v;
        v[0] = (_Float16)a.x; v[1] = (_Float16)a.y; v[2] = (_Float16)a.z; v[3] = (_Float16)a.w;
        v[4] = (_Float16)b.x; v[5] = (_Float16)b.y; v[6] = (_Float16)b.z; v[7] = (_Float16)b.w;
        ((f16x8*)xh)[i] = v;
        return;
    }

    const float* W = (z == 0) ? W0 : (z == 1) ? W1 : (z == 2) ? W2 : W3;
    _Float16*    T = (z == 0) ? T0 : (z == 1) ? T1 : (z == 2) ? T2 : T3;

    const int nb = blockIdx.x * 64;
    const int kb = blockIdx.y * 64;
    const int tr = tid >> 4;
    const int tc = (tid & 15) << 2;

    #pragma unroll
    for (int rr = 0; rr < 4; ++rr) {
        const int k = kb + rr * 16 + tr;
        const float4 v = *(const float4*)&W[(size_t)k * DM + nb + tc];
        t[rr * 16 + tr][tc + 0] = v.x;
        t[rr * 16 + tr][tc + 1] = v.y;
        t[rr * 16 + tr][tc + 2] = v.z;
        t[rr * 16 + tr][tc + 3] = v.w;
    }
    __syncthreads();
    #pragma unroll
    for (int rr = 0; rr < 4; ++rr) {
        const int n = nb + rr * 16 + tr;
        f16x4 v;
        #pragma unroll
        for (int j = 0; j < 4; ++j)
            v[j] = (_Float16)t[tc + j][rr * 16 + tr];
        *(f16x4*)&T[(size_t)n * DM + kb + tc] = v;
    }
}

// ---------------------------------------------------------------------------
// Double-buffered MFMA GEMM. Tile BM x 128 (BM = WGR*WTR*16), BK = 64,
// 4 waves in WGR x WGC grid, each wave WTR x WTC mfma tiles.
// K-chunks XOR-swizzled in LDS: LDS[r][j] holds global chunk j^(r&7), so
// global_load_lds stays lane-contiguous AND ds_read_b128 is conflict-free.
// One __syncthreads per K-tile; prefetch for tile k+1 issued right after the
// barrier overlaps the ds_read+MFMA of tile k.
// grid.x = which*16 + colblock (fused triple), grid.y = rowblock.
template<int WGR, int WGC, int WTR, int WTC, bool F16OUT>
__global__ __launch_bounds__(256, 3) void gemm_db(
    const _Float16* __restrict__ A,
    const _Float16* __restrict__ Bt0, const float* __restrict__ b0, void* __restrict__ C0,
    const _Float16* __restrict__ Bt1, const float* __restrict__ b1, void* __restrict__ C1,
    const _Float16* __restrict__ Bt2, const float* __restrict__ b2, void* __restrict__ C2)
{
    constexpr int BM  = WGR * WTR * 16;
    constexpr int BN  = WGC * WTC * 16;
    static_assert(BN == 128, "col tile must be 128");
    constexpr int NA  = BM / 8;          // A chunks (8 rows x 64 k = 1 KB each)
    constexpr int NB  = 16;              // B chunks
    constexpr int NC  = NA + NB;
    constexpr int CPW = NC / 4;          // chunks per wave
    static_assert(NC % 4 == 0);
    constexpr int BUF = (BM + 128) * 64; // fp16 elements per buffer

    __shared__ _Float16 smem[2 * BUF];

    const int which = blockIdx.x >> 4;
    const int bn    = (blockIdx.x & 15) * 128;
    const int bm    = blockIdx.y * BM;

    const _Float16* Bt   = (which == 0) ? Bt0 : (which == 1) ? Bt1 : Bt2;
    const float*    bias = (which == 0) ? b0  : (which == 1) ? b1  : b2;
    void*           C    = (which == 0) ? C0  : (which == 1) ? C1  : C2;

    const int tid  = threadIdx.x;
    const int lane = tid & 63;
    const int wv   = tid >> 6;                    // 0..3
    const int wr   = (wv / WGC) * (WTR * 16);
    const int wc   = (wv % WGC) * (WTC * 16);
    const int lr   = lane & 15;
    const int lk   = lane >> 4;                   // 0..3
    const int rx   = lr & 7;

    // ---- staging setup: wave wv owns chunks [wv*CPW, wv*CPW+CPW) ----
    const _Float16* gsrc[CPW];
    int             loff[CPW];
    #pragma unroll
    for (int p = 0; p < CPW; ++p) {
        const int c   = wv * CPW + p;
        const int kch = ((lane & 7) ^ (lane >> 3)) << 3;   // swizzled k-offset
        if (c < NA) {
            const int rl = c * 8 + (lane >> 3);
            gsrc[p] = A + (size_t)(bm + rl) * DM + kch;
            loff[p] = c * 512 + lane * 8;
        } else {
            const int rl = (c - NA) * 8 + (lane >> 3);
            gsrc[p] = Bt + (size_t)(bn + rl) * DM + kch;
            loff[p] = BM * 64 + (c - NA) * 512 + lane * 8;
        }
    }

    // ---- fragment LDS offsets (element units, within a buffer) ----
    int offA[WTR][2], offB[WTC][2];
    #pragma unroll
    for (int ks = 0; ks < 2; ++ks) {
        const int sw = (((ks << 2) | lk) ^ rx) << 3;
        #pragma unroll
        for (int i = 0; i < WTR; ++i)
            offA[i][ks] = (wr + i * 16 + lr) * 64 + sw;
        #pragma unroll
        for (int j = 0; j < WTC; ++j)
            offB[j][ks] = BM * 64 + (wc + j * 16 + lr) * 64 + sw;
    }

    f32x4 acc[WTR][WTC] = {};

    auto prefetch = [&](int buf) {
        #pragma unroll
        for (int p = 0; p < CPW; ++p) {
            __builtin_amdgcn_global_load_lds(
                (const __attribute__((address_space(1))) void*)gsrc[p],
                (__attribute__((address_space(3))) void*)(smem + buf * BUF + loff[p]),
                16, 0, 0);
            gsrc[p] += 64;
        }
    };

    auto compute = [&](int buf) {
        const _Float16* base = smem + buf * BUF;
        #pragma unroll
        for (int ks = 0; ks < 2; ++ks) {
            f16x8 aF[WTR], bF[WTC];
            #pragma unroll
            for (int i = 0; i < WTR; ++i)
                aF[i] = *(const f16x8*)&base[offA[i][ks]];
            #pragma unroll
            for (int j = 0; j < WTC; ++j)
                bF[j] = *(const f16x8*)&base[offB[j][ks]];
            #pragma unroll
            for (int i = 0; i < WTR; ++i)
                #pragma unroll
                for (int j = 0; j < WTC; ++j)
                    acc[i][j] = __builtin_amdgcn_mfma_f32_16x16x32_f16(aF[i], bF[j], acc[i][j], 0, 0, 0);
        }
    };

    prefetch(0);                       // tile 0 -> buf0
    #pragma unroll 1
    for (int it2 = 0; it2 < 16; ++it2) {
        __syncthreads();               // buf0 writes done / buf1 reads done
        prefetch(1);                   // tile 2*it2+1 -> buf1 (flies over compute)
        compute(0);                    // tile 2*it2
        __syncthreads();               // buf1 writes done / buf0 reads done
        if (it2 < 15) prefetch(0);     // tile 2*it2+2 -> buf0
        compute(1);                    // tile 2*it2+1
    }

    // ---- epilogue: C/D layout col = lane&15, row = (lane>>4)*4 + reg ----
    #pragma unroll
    for (int i = 0; i < WTR; ++i) {
        #pragma unroll
        for (int j = 0; j < WTC; ++j) {
            const int col = bn + wc + j * 16 + lr;
            const float bv = bias[col];
            #pragma unroll
            for (int r = 0; r < 4; ++r) {
                const int row = bm + wr + i * 16 + lk * 4 + r;
                const float v = acc[i][j][r] + bv;
                if (F16OUT)
                    ((_Float16*)C)[(size_t)row * DM + col] = (_Float16)v;
                else
                    ((float*)C)[(size_t)row * DM + col] = v;
            }
        }
    }
}

// ---------------------------------------------------------------------------
// MFMA attention: one block per token, 4 waves, wave wv owns heads
// [64wv, 64wv+64). S^T = K.Q^T via mfma (K=8 zero-padded), exp in fp32,
// pack to fp16 in LDS (wave-private region, no barrier), O = A.V via mfma.
__global__ __launch_bounds__(256) void attn_mfma(
    const _Float16* __restrict__ Qh, const _Float16* __restrict__ Kh,
    const _Float16* __restrict__ Vh, _Float16* __restrict__ Oh)
{
    __shared__ _Float16 Vt[8][264];      // V transposed [d][g], padded
    __shared__ _Float16 Al[256][72];     // exp(S) [h][g-chunk 64], padded (36 KB)
    __shared__ _Float16 Ot[256][8];      // O bounce [h][d]

    const int t    = blockIdx.x;
    const int tid  = threadIdx.x;
    const int lane = tid & 63;
    const int wv   = tid >> 6;
    const int col  = lane & 15;
    const int quad = lane >> 4;
    const int hbase = wv * 64;

    const _Float16* qb = Qh + (size_t)t * DM;
    const _Float16* kb = Kh + (size_t)t * DM;
    const _Float16* vb = Vh + (size_t)t * DM;

    {
        const f16x8 v = *(const f16x8*)(vb + tid * 8);
        #pragma unroll
        for (int d = 0; d < 8; ++d) Vt[d][tid] = v[d];
    }

    f16x8 qf[4];
    #pragma unroll
    for (int ht = 0; ht < 4; ++ht) {
        f16x8 v = {};
        if (quad == 0)
            v = *(const f16x8*)(qb + (hbase + ht * 16 + col) * 8);
        #pragma unroll
        for (int j = 0; j < 8; ++j) qf[ht][j] = v[j] * (_Float16)SCALE;
    }

    __syncthreads();   // Vt visible to all waves

    const f32x4 zf = {};
    float rsum[4] = {};
    f32x4 oacc[4] = {};

    #pragma unroll 1
    for (int c = 0; c < 4; ++c) {
        const int gchunk = c * 64;

        f16x8 kf[4];
        #pragma unroll
        for (int gt = 0; gt < 4; ++gt) {
            f16x8 v = {};
            if (quad == 0)
                v = *(const f16x8*)(kb + (gchunk + gt * 16 + col) * 8);
            kf[gt] = v;
        }

        f32x4 s[4][4];
        #pragma unroll
        for (int gt = 0; gt < 4; ++gt)
            #pragma unroll
            for (int ht = 0; ht < 4; ++ht)
                s[gt][ht] = __builtin_amdgcn_mfma_f32_16x16x32_f16(kf[gt], qf[ht], zf, 0, 0, 0);

        #pragma unroll
        for (int gt = 0; gt < 4; ++gt) {
            #pragma unroll
            for (int ht = 0; ht < 4; ++ht) {
                f16x4 e4;
                #pragma unroll
                for (int r = 0; r < 4; ++r) {
                    e4[r] = (_Float16)__expf(s[gt][ht][r]);
                    rsum[ht] += (float)e4[r];
                }
                *(f16x4*)&Al[hbase + ht * 16 + col][gt * 16 + quad * 4] = e4;
            }
        }

        #pragma unroll
        for (int ks = 0; ks < 2; ++ks) {
            f16x8 vf = {};
            if (col < 8)
                vf = *(const f16x8*)&Vt[col][gchunk + ks * 32 + quad * 8];
            #pragma unroll
            for (int ht = 0; ht < 4; ++ht) {
                const f16x8 af = *(const f16x8*)&Al[hbase + ht * 16 + col][ks * 32 + quad * 8];
                oacc[ht] = __builtin_amdgcn_mfma_f32_16x16x32_f16(af, vf, oacc[ht], 0, 0, 0);
            }
        }
    }

    #pragma unroll
    for (int ht = 0; ht < 4; ++ht) {
        rsum[ht] += __shfl_xor(rsum[ht], 16, 64);
        rsum[ht] += __shfl_xor(rsum[ht], 32, 64);
    }

    #pragma unroll
    for (int ht = 0; ht < 4; ++ht) {
        #pragma unroll
        for (int r = 0; r < 4; ++r) {
            const float sh = __shfl(rsum[ht], quad * 4 + r, 64);
            const float v  = oacc[ht][r] / sh;
            if (col < 8)
                Ot[hbase + ht * 16 + quad * 4 + r][col] = (_Float16)v;
        }
    }
    const f16x8 ov = *(const f16x8*)&Ot[tid][0];
    *(f16x8*)(Oh + (size_t)t * DM + tid * 8) = ov;
}

// ---------------------------------------------------------------------------
extern "C" void kernel_launch(void* const* d_in, const int* in_sizes, int n_in,
                              void* d_out, int out_size, void* d_ws, size_t ws_size,
                              hipStream_t stream)
{
    const float* x  = (const float*)d_in[0];
    // d_in[1] = phase_shift: cancels analytically (cos^2 + sin^2 = 1), unused
    const float* Wq = (const float*)d_in[2];
    const float* bq = (const float*)d_in[3];
    const float* Wk = (const float*)d_in[4];
    const float* bk = (const float*)d_in[5];
    const float* Wv = (const float*)d_in[6];
    const float* bv = (const float*)d_in[7];
    const float* Wo = (const float*)d_in[8];
    const float* bo = (const float*)d_in[9];
    float* out = (float*)d_out;

    char* ws = (char*)d_ws;
    _Float16* xh  = (_Float16*)(ws);                 // 4 MB
    _Float16* Wtq = (_Float16*)(ws + (4u  << 20));   // 8 MB
    _Float16* Wtk = (_Float16*)(ws + (12u << 20));   // 8 MB
    _Float16* Wtv = (_Float16*)(ws + (20u << 20));   // 8 MB
    _Float16* Wto = (_Float16*)(ws + (28u << 20));   // 8 MB
    _Float16* Qh  = (_Float16*)(ws + (36u << 20));   // 4 MB
    _Float16* Kh  = (_Float16*)(ws + (40u << 20));   // 4 MB
    _Float16* Vh  = (_Float16*)(ws + (44u << 20));   // 4 MB
    _Float16* Oh  = (_Float16*)(ws + (48u << 20));   // 4 MB

    // cast x + cast/transpose 4 weights in one launch
    prep<<<dim3(32, 32, 5), dim3(256), 0, stream>>>(
        x, xh, Wq, Wk, Wv, Wo, Wtq, Wtk, Wtv, Wto);

    // QKV fused: 64x128 tiles, BK=64, dbuf. grid 48 x 16 = 768 blocks (3/CU)
    gemm_db<2, 2, 2, 4, true><<<dim3(48, 16), dim3(256), 0, stream>>>(xh,
        Wtq, bq, (void*)Qh,
        Wtk, bk, (void*)Kh,
        Wtv, bv, (void*)Vh);

    attn_mfma<<<dim3(M_TOK), dim3(256), 0, stream>>>(Qh, Kh, Vh, Oh);

    // output projection: 32x128 tiles, BK=64, dbuf. grid 16 x 32 = 512 blocks
    gemm_db<1, 4, 2, 2, false><<<dim3(16, 32), dim3(256), 0, stream>>>(Oh,
        Wto, bo, (void*)out,
        Wto, bo, (void*)out,
        Wto, bo, (void*)out);
}